// Round 11
// baseline (1340.041 us; speedup 1.0000x reference)
//
#include <hip/hip_runtime.h>

typedef __attribute__((ext_vector_type(8)))  short s8b;      // 8 x bf16
typedef __attribute__((ext_vector_type(8)))  _Float16 f16x8; // 8 x f16
typedef __attribute__((ext_vector_type(16))) float v16f;     // 32x32 f32 acc
typedef __attribute__((ext_vector_type(4)))  float v4f;
typedef __attribute__((ext_vector_type(4)))  unsigned int u32x4;
typedef unsigned short u16;
typedef unsigned int u32;

__device__ __forceinline__ float clamp01(float v) {
  return __builtin_fminf(__builtin_fmaxf(v, 0.0f), 1.0f);
}
__device__ __forceinline__ u16 f16bits(float v) {
  _Float16 h = (_Float16)v;
  return __builtin_bit_cast(u16, h);
}
__device__ __forceinline__ void split1(float f, u16 &h, u16 &l) {
  unsigned u = __builtin_bit_cast(unsigned, f);
  unsigned hu = u & 0xffff0000u;
  float lf = f - __builtin_bit_cast(float, hu);
  h = (u16)(u >> 16);
  l = (u16)(__builtin_bit_cast(unsigned, lf) >> 16);
}

__device__ __forceinline__ v16f mfma32bf(s8b a, s8b b, v16f c) {
  return __builtin_amdgcn_mfma_f32_32x32x16_bf16(a, b, c, 0, 0, 0);
}
__device__ __forceinline__ v16f mfma32h(f16x8 a, f16x8 b, v16f c) {
  return __builtin_amdgcn_mfma_f32_32x32x16_f16(a, b, c, 0, 0, 0);
}
__device__ __forceinline__ v4f mfma16h(f16x8 a, f16x8 b, v4f c) {
  return __builtin_amdgcn_mfma_f32_16x16x32_f16(a, b, c, 0, 0, 0);
}

// swizzled u16 index in a [R][256] tile: 8-elem chunk c=col>>3 -> c^(row&7)
__device__ __forceinline__ int sw_idx(int row, int col) {
  return row * 256 + ((((col >> 3) ^ (row & 7))) << 3) + (col & 7);
}

// ---------------- prep kernels ----------------------------------------------
// W2/W3 -> f16 frag chunks: chunk i=(w*16+kt)*64+l holds 8 f16:
//   col=(w*32+(l&31)), k=kt*16+(l>>5)*8 .. +7
// W0 -> [16][256] f16 (n<10 valid); W4 -> bf16 h/l (for k_drive)
__global__ void k_prep_w(const float* __restrict__ W2, const float* __restrict__ W3,
                         const float* __restrict__ W4, const float* __restrict__ W0,
                         u16* __restrict__ w2f, u16* __restrict__ w3f,
                         u16* __restrict__ w0f,
                         u16* __restrict__ w4h, u16* __restrict__ w4l) {
  int i = blockIdx.x * 256 + threadIdx.x;
  if (i < 8192) {     // fragment chunks
    int w = i >> 10, kt = (i >> 6) & 15, l = i & 63;
    int m = l & 31, g = l >> 5;
    int src = (w * 32 + m) * 256 + kt * 16 + g * 8;
    u16 a2[8], a3[8];
    #pragma unroll
    for (int j = 0; j < 8; ++j) {
      a2[j] = f16bits(W2[src + j]);
      a3[j] = f16bits(W3[src + j]);
    }
    #pragma unroll
    for (int j = 0; j < 8; ++j) { w2f[i * 8 + j] = a2[j]; w3f[i * 8 + j] = a3[j]; }
  }
  if (i < 4096) {                           // W0 padded [16][256]
    int n = i >> 8, k = i & 255;
    float v = (n < 10) ? W0[n * 256 + k] : 0.0f;
    w0f[i] = f16bits(v);
  }
  if (i < 200704) {
    u16 h, lo;
    split1(W4[i], h, lo); w4h[i] = h; w4l[i] = lo;
  }
}

// W1 frags: chunk i=w*64+l holds 8 f16: col=w*32+(l&31), k=(l>>5)*8+j (k<10 valid)
__global__ void k_prep_small(const float* __restrict__ W1, const float* __restrict__ b0,
                             u16* __restrict__ w1f, float* __restrict__ b0p) {
  int i = blockIdx.x * 256 + threadIdx.x;
  if (i < 512) {
    int w = i >> 6, l = i & 63, m = l & 31, g = l >> 5;
    int col = w * 32 + m;
    #pragma unroll
    for (int j = 0; j < 8; ++j) {
      int k = g * 8 + j;
      float f = (k < 10) ? W1[col * 10 + k] : 0.0f;
      w1f[i * 8 + j] = f16bits(f);
    }
  } else if (i < 528) {
    int k = i - 512;
    b0p[k] = (k < 10) ? b0[k] : 0.0f;
  }
}

// ---------------- drive = data @ W4^T + b4 (bf16 3-pass, once) ---------------
__device__ __forceinline__ void split_pack8(v4f x0, v4f x1, s8b &hi, s8b &lo) {
  float f[8];
  #pragma unroll
  for (int j = 0; j < 4; ++j) { f[j] = x0[j]; f[4 + j] = x1[j]; }
  u32x4 vh, vl;
  #pragma unroll
  for (int j = 0; j < 4; ++j) {
    unsigned u0 = __builtin_bit_cast(unsigned, f[2 * j]);
    unsigned u1 = __builtin_bit_cast(unsigned, f[2 * j + 1]);
    unsigned h0 = u0 & 0xffff0000u, h1 = u1 & 0xffff0000u;
    float l0 = f[2 * j]     - __builtin_bit_cast(float, h0);
    float l1 = f[2 * j + 1] - __builtin_bit_cast(float, h1);
    vh[j] = (u0 >> 16) | h1;
    vl[j] = (__builtin_bit_cast(unsigned, l0) >> 16) |
            (__builtin_bit_cast(unsigned, l1) & 0xffff0000u);
  }
  hi = __builtin_bit_cast(s8b, vh);
  lo = __builtin_bit_cast(s8b, vl);
}

__global__ void __launch_bounds__(256, 1) k_drive(
    const float* __restrict__ data, const u16* __restrict__ w4h,
    const u16* __restrict__ w4l, const float* __restrict__ b4,
    float* __restrict__ drive) {
  const int tid = threadIdx.x;
  const int w = tid >> 6, l = tid & 63;
  const int m = l & 31, g = l >> 5;
  const int rb = blockIdx.x * 64;
  const int nbase = w * 64;
  float b4v0 = b4[nbase + m], b4v1 = b4[nbase + 32 + m];
  v16f acc[2][2];
  #pragma unroll
  for (int r = 0; r < 16; ++r) {
    acc[0][0][r] = b4v0; acc[0][1][r] = b4v1;
    acc[1][0][r] = b4v0; acc[1][1][r] = b4v1;
  }
  for (int kt = 0; kt < 49; ++kt) {
    int k0 = kt * 16 + g * 8;
    s8b aH[2], aL[2], bH[2], bL[2];
    #pragma unroll
    for (int mt = 0; mt < 2; ++mt) {
      const float* p = data + (size_t)(rb + 32 * mt + m) * 784 + k0;
      v4f x0 = *(const v4f*)p;
      v4f x1 = *(const v4f*)(p + 4);
      split_pack8(x0, x1, aH[mt], aL[mt]);
    }
    #pragma unroll
    for (int nt = 0; nt < 2; ++nt) {
      int off = (nbase + 32 * nt + m) * 784 + k0;
      bH[nt] = *(const s8b*)(w4h + off);
      bL[nt] = *(const s8b*)(w4l + off);
    }
    #pragma unroll
    for (int mt = 0; mt < 2; ++mt)
      #pragma unroll
      for (int nt = 0; nt < 2; ++nt) {
        acc[mt][nt] = mfma32bf(aH[mt], bH[nt], acc[mt][nt]);
        acc[mt][nt] = mfma32bf(aL[mt], bH[nt], acc[mt][nt]);
        acc[mt][nt] = mfma32bf(aH[mt], bL[nt], acc[mt][nt]);
      }
  }
  #pragma unroll
  for (int mt = 0; mt < 2; ++mt)
    #pragma unroll
    for (int nt = 0; nt < 2; ++nt)
      #pragma unroll
      for (int r = 0; r < 16; ++r) {
        int row = rb + 32 * mt + (r & 3) + 8 * (r >> 2) + 4 * g;
        int col = nbase + 32 * nt + m;
        drive[(size_t)row * 256 + col] = acc[mt][nt][r];
      }
}

// ---------------- main persistent stepper (f16, weights in AGPRs) ------------
__global__ void __launch_bounds__(512, 2) k_main(
    const float* __restrict__ s0g, const float* __restrict__ s1g,
    const float* __restrict__ s2g, const float* __restrict__ b2,
    const int* __restrict__ Tp,
    const u16* __restrict__ w2f, const u16* __restrict__ w3f,
    const u16* __restrict__ w0f, const u16* __restrict__ w1f,
    const float* __restrict__ b0p, const float* __restrict__ drive,
    float* __restrict__ out0, float* __restrict__ out1, float* __restrict__ out2) {
  extern __shared__ u16 smem[];
  u16* s1A = smem;                  // [64][256] f16 swizzled, 32 KB each
  u16* s1B = smem + 16384;
  u16* s2A = smem + 32768;
  u16* s2B = smem + 49152;
  u16* s0A = smem + 65536;          // [64][16] f16, 2 KB each
  u16* s0B = smem + 66560;
  u16* w0s = smem + 67584;          // [16][256] f16 swizzled, 8 KB
  // total 71680 u16 = 143360 B

  const int tid = threadIdx.x;
  const int w = tid >> 6, l = tid & 63;
  const int m = l & 31, g = l >> 5;
  const int m16 = l & 15, g4 = l >> 4;
  const int rb = blockIdx.x * 64;
  const int nbase = w * 32;
  const int col = nbase + m;

  // ---- stage W2/W3 fragments, pinned into AGPRs (128 AGPR total) ----
  u32x4 w2A[16], w3A[16];
  {
    const int cb = (w * 16) * 64 + l;     // chunk base
    #pragma unroll
    for (int kt = 0; kt < 16; ++kt) {
      w2A[kt] = *(const u32x4*)(w2f + (cb + kt * 64) * 8);
      w3A[kt] = *(const u32x4*)(w3f + (cb + kt * 64) * 8);
    }
  }
  #define PIN4(A, i0) asm volatile("" : "+a"(A[i0]), "+a"(A[i0+1]), "+a"(A[i0+2]), "+a"(A[i0+3]))
  PIN4(w2A, 0); PIN4(w2A, 4); PIN4(w2A, 8); PIN4(w2A, 12);
  PIN4(w3A, 0); PIN4(w3A, 4); PIN4(w3A, 8); PIN4(w3A, 12);

  const f16x8 w1F = *(const f16x8*)(w1f + ((w << 6) + l) * 8);

  // ---- init LDS states ----
  for (int i = tid; i < 16384; i += 512) {
    int row = i >> 8, c = i & 255;
    int idx = sw_idx(row, c);
    s1A[idx] = f16bits(s1g[(size_t)(rb + row) * 256 + c]);
    s2A[idx] = f16bits(s2g[(size_t)(rb + row) * 256 + c]);
  }
  for (int i = tid; i < 1024; i += 512) {
    int row = i >> 4, c = i & 15;
    float v = (c < 10) ? s0g[(rb + row) * 10 + c] : 0.0f;
    s0A[i] = f16bits(v);
    s0B[i] = 0;                     // f16 zero
  }
  if (tid < 512) {                  // stage W0 into LDS, swizzled 8-elem chunks
    int r = tid >> 5, c = tid & 31;
    int dst = r * 256 + ((c ^ (r & 7)) << 3);
    #pragma unroll
    for (int j = 0; j < 8; ++j) w0s[dst + j] = w0f[r * 256 + c * 8 + j];
  }

  const float b2v = b2[col];
  const float b0v = b0p[m16];
  float dr[2][16];
  #pragma unroll
  for (int mt = 0; mt < 2; ++mt)
    #pragma unroll
    for (int r = 0; r < 16; ++r) {
      int row = rb + 32 * mt + (r & 3) + 8 * (r >> 2) + 4 * g;
      dr[mt][r] = drive[(size_t)row * 256 + col];
    }
  const int T = Tp[0];
  const int cq = col >> 3, cw = col & 7;
  const int rs = (m & 7) << 3;      // A-read swizzle shift ((m+32)&7 == m&7)
  __syncthreads();

  u16 *s1c = s1A, *s1n = s1B, *s2c = s2A, *s2n = s2B;
  u16 *s0c = s0A, *s0n = s0B;

  for (int t = 0; t < T; ++t) {
    const bool last = (t == T - 1);
    // re-pin weights each iteration: kills any hoisted arch-VGPR shadows
    PIN4(w2A, 0); PIN4(w2A, 4); PIN4(w2A, 8); PIN4(w2A, 12);
    PIN4(w3A, 0); PIN4(w3A, 4); PIN4(w3A, 8); PIN4(w3A, 12);

    // ---- n2 = clamp(drive + s1 @ W3^T) ----
    v16f acc2[2];
    #pragma unroll
    for (int r = 0; r < 16; ++r) { acc2[0][r] = dr[0][r]; acc2[1][r] = dr[1][r]; }
    {
      const u16* a0p = s1c + m * 256;
      const u16* a1p = s1c + (m + 32) * 256;
      #pragma unroll
      for (int kt = 0; kt < 16; ++kt) {
        const int off = ((2 * kt + g) << 3) ^ rs;
        f16x8 a0 = *(const f16x8*)(a0p + off);
        f16x8 a1 = *(const f16x8*)(a1p + off);
        f16x8 bb = __builtin_bit_cast(f16x8, w3A[kt]);
        acc2[0] = mfma32h(a0, bb, acc2[0]);
        acc2[1] = mfma32h(a1, bb, acc2[1]);
      }
    }
    #pragma unroll
    for (int mt = 0; mt < 2; ++mt)
      #pragma unroll
      for (int r = 0; r < 16; ++r) {
        float v = clamp01(acc2[mt][r]);
        int row = 32 * mt + (r & 3) + 8 * (r >> 2) + 4 * g;
        s2n[row * 256 + ((cq ^ (row & 7)) << 3) + cw] = f16bits(v);
        if (last) out2[(size_t)(rb + row) * 256 + col] = v;
      }

    // ---- n1 = clamp(b2 + s0 @ W1^T + s2 @ W2^T) ----
    v16f acc1[2];
    #pragma unroll
    for (int r = 0; r < 16; ++r) { acc1[0][r] = b2v; acc1[1][r] = b2v; }
    {
      f16x8 a0s = *(const f16x8*)(s0c + m * 16 + g * 8);
      f16x8 a1s = *(const f16x8*)(s0c + (m + 32) * 16 + g * 8);
      acc1[0] = mfma32h(a0s, w1F, acc1[0]);
      acc1[1] = mfma32h(a1s, w1F, acc1[1]);
      const u16* a0p = s2c + m * 256;
      const u16* a1p = s2c + (m + 32) * 256;
      #pragma unroll
      for (int kt = 0; kt < 16; ++kt) {
        const int off = ((2 * kt + g) << 3) ^ rs;
        f16x8 a0 = *(const f16x8*)(a0p + off);
        f16x8 a1 = *(const f16x8*)(a1p + off);
        f16x8 bb = __builtin_bit_cast(f16x8, w2A[kt]);
        acc1[0] = mfma32h(a0, bb, acc1[0]);
        acc1[1] = mfma32h(a1, bb, acc1[1]);
      }
    }
    #pragma unroll
    for (int mt = 0; mt < 2; ++mt)
      #pragma unroll
      for (int r = 0; r < 16; ++r) {
        float v = clamp01(acc1[mt][r]);
        int row = 32 * mt + (r & 3) + 8 * (r >> 2) + 4 * g;
        s1n[row * 256 + ((cq ^ (row & 7)) << 3) + cw] = f16bits(v);
        if (last) out1[(size_t)(rb + row) * 256 + col] = v;
      }

    // ---- n0 = clamp(b0 + s1 @ W0^T), waves 0-3, 16x16x32 f16 ----
    if (w < 4) {
      const int arow = 16 * w + m16;
      const int rsh = (arow & 7) << 3;
      const u16* ap = s1c + arow * 256;
      v4f acc0;
      #pragma unroll
      for (int r = 0; r < 4; ++r) acc0[r] = b0v;
      #pragma unroll
      for (int kt = 0; kt < 8; ++kt) {
        const int ch = 4 * kt + g4;
        f16x8 a = *(const f16x8*)(ap + ((ch << 3) ^ rsh));
        f16x8 b = *(const f16x8*)(w0s + m16 * 256 + ((ch ^ (m16 & 7)) << 3));
        acc0 = mfma16h(a, b, acc0);
      }
      #pragma unroll
      for (int r = 0; r < 4; ++r) {
        float v = clamp01(acc0[r]);
        int row = 16 * w + g4 * 4 + r;
        if (m16 < 10) {
          s0n[row * 16 + m16] = f16bits(v);
          if (last) out0[(rb + row) * 10 + m16] = v;
        }
      }
    }

    __syncthreads();   // next-state buffers fully written; old fully read
    u16* tp;
    tp = s1c; s1c = s1n; s1n = tp;
    tp = s2c; s2c = s2n; s2n = tp;
    tp = s0c; s0c = s0n; s0n = tp;
  }
  #undef PIN4
}

// ---------------- launcher ---------------------------------------------------
extern "C" void kernel_launch(void* const* d_in, const int* in_sizes, int n_in,
                              void* d_out, int out_size, void* d_ws, size_t ws_size,
                              hipStream_t stream) {
  const float* data = (const float*)d_in[0];
  const float* s0g  = (const float*)d_in[1];
  const float* s1g  = (const float*)d_in[2];
  const float* s2g  = (const float*)d_in[3];
  const float* W0   = (const float*)d_in[4];
  const float* b0   = (const float*)d_in[5];
  const float* W1   = (const float*)d_in[6];
  const float* W2   = (const float*)d_in[7];
  const float* b2   = (const float*)d_in[8];
  const float* W3   = (const float*)d_in[9];
  const float* W4   = (const float*)d_in[10];
  const float* b4   = (const float*)d_in[11];
  const int*   Tp   = (const int*)d_in[12];

  char* ws = (char*)d_ws;
  float* drive = (float*)ws;                                  // 16 MB f32
  size_t off = 16777216;
  u16* w2f = (u16*)(ws + off); off += 131072;
  u16* w3f = (u16*)(ws + off); off += 131072;
  u16* w0f = (u16*)(ws + off); off += 8192;
  u16* w1f = (u16*)(ws + off); off += 8192;
  u16* w4h = (u16*)(ws + off); off += 401408;
  u16* w4l = (u16*)(ws + off); off += 401408;
  float* b0p = (float*)(ws + off); off += 64;

  float* out0 = (float*)d_out;
  float* out1 = out0 + 16384 * 10;
  float* out2 = out1 + 16384 * 256;

  hipFuncSetAttribute((const void*)k_main,
                      hipFuncAttributeMaxDynamicSharedMemorySize, 143360);

  k_prep_w<<<784, 256, 0, stream>>>(W2, W3, W4, W0, w2f, w3f, w0f, w4h, w4l);
  k_prep_small<<<3, 256, 0, stream>>>(W1, b0, w1f, b0p);
  k_drive<<<256, 256, 0, stream>>>(data, w4h, w4l, b4, drive);
  k_main<<<256, 512, 143360, stream>>>(s0g, s1g, s2g, b2, Tp,
      w2f, w3f, w0f, w1f, b0p, drive, out0, out1, out2);
}

// Round 12
// 376.582 us; speedup vs baseline: 3.5584x; 3.5584x over previous
//
#include <hip/hip_runtime.h>

typedef __attribute__((ext_vector_type(8)))  short s8b;      // 8 x bf16
typedef __attribute__((ext_vector_type(16))) float v16f;     // 32x32 f32 acc
typedef __attribute__((ext_vector_type(4)))  float v4f;
typedef __attribute__((ext_vector_type(4)))  unsigned int u32x4;
typedef __attribute__((ext_vector_type(4)))  int i32x4;      // 16 x i8 operand
typedef __attribute__((ext_vector_type(16))) int i32x16;     // 32x32 i32 acc
typedef unsigned short u16;
typedef unsigned char u8;
typedef unsigned int u32;

#define Q25_ONE (1 << 25)

__device__ __forceinline__ void split1(float f, u16 &h, u16 &l) {
  unsigned u = __builtin_bit_cast(unsigned, f);
  unsigned hu = u & 0xffff0000u;
  float lf = f - __builtin_bit_cast(float, hu);
  h = (u16)(u >> 16);
  l = (u16)(__builtin_bit_cast(unsigned, lf) >> 16);
}

__device__ __forceinline__ v16f mfma32bf(s8b a, s8b b, v16f c) {
  return __builtin_amdgcn_mfma_f32_32x32x16_bf16(a, b, c, 0, 0, 0);
}
__device__ __forceinline__ i32x16 mfma_i8_32(i32x4 a, i32x4 b, i32x16 c) {
  return __builtin_amdgcn_mfma_i32_32x32x32_i8(a, b, c, 0, 0, 0);
}
__device__ __forceinline__ i32x4 mfma_i8_16(i32x4 a, i32x4 b, i32x4 c) {
  return __builtin_amdgcn_mfma_i32_16x16x64_i8(a, b, c, 0, 0, 0);
}

// ---------------- prep kernels ----------------------------------------------
// W2/W3 row-major i8 Q11; W0 padded [16][256] i8 Q11; W4 -> bf16 h/l
__global__ void k_prep_w(const float* __restrict__ W2, const float* __restrict__ W3,
                         const float* __restrict__ W4, const float* __restrict__ W0,
                         signed char* __restrict__ w2q, signed char* __restrict__ w3q,
                         signed char* __restrict__ w0q,
                         u16* __restrict__ w4h, u16* __restrict__ w4l) {
  int i = blockIdx.x * 256 + threadIdx.x;
  if (i < 65536) {
    int q = (int)rintf(W2[i] * 2048.0f);
    q = min(max(q, -127), 127); w2q[i] = (signed char)q;
    q = (int)rintf(W3[i] * 2048.0f);
    q = min(max(q, -127), 127); w3q[i] = (signed char)q;
  }
  if (i < 4096) {                           // W0 padded [16][256]
    int n = i >> 8, k = i & 255;
    float v = (n < 10) ? W0[n * 256 + k] : 0.0f;
    int q = (int)rintf(v * 2048.0f);
    q = min(max(q, -127), 127); w0q[i] = (signed char)q;
  }
  if (i < 200704) {
    u16 h, lo;
    split1(W4[i], h, lo); w4h[i] = h; w4l[i] = lo;
  }
}

// W1 padded [256 out][32 k] i8 Q11 (k<10 valid); b0 padded [16]
__global__ void k_prep_small(const float* __restrict__ W1, const float* __restrict__ b0,
                             signed char* __restrict__ w1q, float* __restrict__ b0p) {
  int i = blockIdx.x * 256 + threadIdx.x;
  if (i < 8192) {
    int n = i >> 5, k = i & 31;
    float v = (k < 10) ? W1[n * 10 + k] : 0.0f;
    int q = (int)rintf(v * 2048.0f);
    q = min(max(q, -127), 127); w1q[i] = (signed char)q;
  } else if (i < 8208) {
    int k = i - 8192;
    b0p[k] = (k < 10) ? b0[k] : 0.0f;
  }
}

// ---------------- drive = data @ W4^T + b4 (bf16 3-pass, once) ---------------
// output: i32 Q25 row-major
__device__ __forceinline__ void split_pack8(v4f x0, v4f x1, s8b &hi, s8b &lo) {
  float f[8];
  #pragma unroll
  for (int j = 0; j < 4; ++j) { f[j] = x0[j]; f[4 + j] = x1[j]; }
  u32x4 vh, vl;
  #pragma unroll
  for (int j = 0; j < 4; ++j) {
    unsigned u0 = __builtin_bit_cast(unsigned, f[2 * j]);
    unsigned u1 = __builtin_bit_cast(unsigned, f[2 * j + 1]);
    unsigned h0 = u0 & 0xffff0000u, h1 = u1 & 0xffff0000u;
    float l0 = f[2 * j]     - __builtin_bit_cast(float, h0);
    float l1 = f[2 * j + 1] - __builtin_bit_cast(float, h1);
    vh[j] = (u0 >> 16) | h1;
    vl[j] = (__builtin_bit_cast(unsigned, l0) >> 16) |
            (__builtin_bit_cast(unsigned, l1) & 0xffff0000u);
  }
  hi = __builtin_bit_cast(s8b, vh);
  lo = __builtin_bit_cast(s8b, vl);
}

__global__ void __launch_bounds__(256, 1) k_drive(
    const float* __restrict__ data, const u16* __restrict__ w4h,
    const u16* __restrict__ w4l, const float* __restrict__ b4,
    int* __restrict__ drive) {
  const int tid = threadIdx.x;
  const int w = tid >> 6, l = tid & 63;
  const int m = l & 31, g = l >> 5;
  const int rb = blockIdx.x * 64;
  const int nbase = w * 64;
  float b4v0 = b4[nbase + m], b4v1 = b4[nbase + 32 + m];
  v16f acc[2][2];
  #pragma unroll
  for (int r = 0; r < 16; ++r) {
    acc[0][0][r] = b4v0; acc[0][1][r] = b4v1;
    acc[1][0][r] = b4v0; acc[1][1][r] = b4v1;
  }
  for (int kt = 0; kt < 49; ++kt) {
    int k0 = kt * 16 + g * 8;
    s8b aH[2], aL[2], bH[2], bL[2];
    #pragma unroll
    for (int mt = 0; mt < 2; ++mt) {
      const float* p = data + (size_t)(rb + 32 * mt + m) * 784 + k0;
      v4f x0 = *(const v4f*)p;
      v4f x1 = *(const v4f*)(p + 4);
      split_pack8(x0, x1, aH[mt], aL[mt]);
    }
    #pragma unroll
    for (int nt = 0; nt < 2; ++nt) {
      int off = (nbase + 32 * nt + m) * 784 + k0;
      bH[nt] = *(const s8b*)(w4h + off);
      bL[nt] = *(const s8b*)(w4l + off);
    }
    #pragma unroll
    for (int mt = 0; mt < 2; ++mt)
      #pragma unroll
      for (int nt = 0; nt < 2; ++nt) {
        acc[mt][nt] = mfma32bf(aH[mt], bH[nt], acc[mt][nt]);
        acc[mt][nt] = mfma32bf(aL[mt], bH[nt], acc[mt][nt]);
        acc[mt][nt] = mfma32bf(aH[mt], bL[nt], acc[mt][nt]);
      }
  }
  #pragma unroll
  for (int mt = 0; mt < 2; ++mt)
    #pragma unroll
    for (int nt = 0; nt < 2; ++nt)
      #pragma unroll
      for (int r = 0; r < 16; ++r) {
        int row = rb + 32 * mt + (r & 3) + 8 * (r >> 2) + 4 * g;
        int col = nbase + 32 * nt + m;
        drive[(size_t)row * 256 + col] = (int)rintf(acc[mt][nt][r] * 33554432.0f);
      }
}

// ---------------- main persistent stepper ------------------------------------
// h/l split i8 state arrays: no unpack VALU. 32-row blocks, 2 blocks/CU.
__global__ void __launch_bounds__(512, 2) k_main(
    const float* __restrict__ s0g, const float* __restrict__ s1g,
    const float* __restrict__ s2g, const float* __restrict__ b2,
    const int* __restrict__ Tp,
    const signed char* __restrict__ w2q, const signed char* __restrict__ w3q,
    const signed char* __restrict__ w0q, const signed char* __restrict__ w1q,
    const float* __restrict__ b0p, const int* __restrict__ drive,
    float* __restrict__ out0, float* __restrict__ out1, float* __restrict__ out2) {
  extern __shared__ u8 sm8[];
  u8* s1hA = sm8;                 // [32][256] i8, 8 KB each
  u8* s1lA = sm8 + 8192;
  u8* s2hA = sm8 + 16384;
  u8* s2lA = sm8 + 24576;
  u8* s1hB = sm8 + 32768;
  u8* s1lB = sm8 + 40960;
  u8* s2hB = sm8 + 49152;
  u8* s2lB = sm8 + 57344;
  u8* s0hA = sm8 + 65536;         // [32][32] i8, 1 KB each (k padded to 32)
  u8* s0lA = sm8 + 66560;
  u8* s0hB = sm8 + 67584;
  u8* s0lB = sm8 + 68608;
  u8* w0s  = sm8 + 69632;         // [16][256] i8 swizzled, 4 KB
  // total 73728 B -> 2 blocks/CU

  const int tid = threadIdx.x;
  const int w = tid >> 6, l = tid & 63;
  const int m = l & 31, g = l >> 5;
  const int m16 = l & 15, g4 = l >> 4;
  const int rb = blockIdx.x * 32;
  const int col = w * 32 + m;

  // ---- stage weights into registers (once): 68 VGPR ----
  i32x4 w2F[8], w3F[8], w1F;
  {
    const int wo = col * 256 + g * 16;
    #pragma unroll
    for (int kt = 0; kt < 8; ++kt) {
      w2F[kt] = *(const i32x4*)(w2q + wo + kt * 32);
      w3F[kt] = *(const i32x4*)(w3q + wo + kt * 32);
    }
    w1F = *(const i32x4*)(w1q + col * 32 + g * 16);
  }

  // ---- init LDS states (h/l split, 16B-chunk XOR swizzle) ----
  for (int i = tid; i < 8192; i += 512) {
    int row = i >> 8, c = i & 255;
    int idx = row * 256 + ((((c >> 4) ^ (row & 15)) << 4)) + (c & 15);
    int q = (int)rintf(s1g[(size_t)(rb + row) * 256 + c] * 16384.0f);
    int h = (q + 128) >> 8;
    s1hA[idx] = (u8)h; s1lA[idx] = (u8)(q - (h << 8));
    q = (int)rintf(s2g[(size_t)(rb + row) * 256 + c] * 16384.0f);
    h = (q + 128) >> 8;
    s2hA[idx] = (u8)h; s2lA[idx] = (u8)(q - (h << 8));
  }
  for (int i = tid; i < 1024; i += 512) {
    int row = i >> 5, c = i & 31;
    float v = (c < 10) ? s0g[(rb + row) * 10 + c] : 0.0f;
    int q = (int)rintf(v * 16384.0f);
    int h = (q + 128) >> 8;
    s0hA[i] = (u8)h; s0lA[i] = (u8)(q - (h << 8));
    s0hB[i] = 0; s0lB[i] = 0;       // pad cols stay zero
  }
  if (tid < 256) {                  // stage W0 into LDS, swizzled 16B chunks
    int r = tid >> 4, c = tid & 15;
    int dst = r * 256 + ((c ^ r) << 4);
    *(i32x4*)(w0s + dst) = *(const i32x4*)(w0q + r * 256 + c * 16);
  }

  const int b2i = (int)rintf(b2[col] * 33554432.0f);      // Q25
  const int b0i = (int)rintf(b0p[m16] * 33554432.0f);     // Q25
  int dr[16];
  {
    const int* drvp = drive + (size_t)rb * 256 + col;
    #pragma unroll
    for (int r = 0; r < 16; ++r) {
      int row = (r & 3) + 8 * (r >> 2) + 4 * g;
      dr[r] = drvp[row * 256];
    }
  }
  const int T = Tp[0];
  const int cc = col >> 4, cb = col & 15;   // write chunk / byte
  const int rs4 = m & 15;                   // A-read swizzle nibble
  float* out1p = out1 + (size_t)rb * 256 + col;
  float* out2p = out2 + (size_t)rb * 256 + col;
  __syncthreads();

  u8 *s1ch = s1hA, *s1cl = s1lA, *s2ch = s2hA, *s2cl = s2lA;
  u8 *s1nh = s1hB, *s1nl = s1lB, *s2nh = s2hB, *s2nl = s2lB;
  u8 *s0ch = s0hA, *s0cl = s0lA, *s0nh = s0hB, *s0nl = s0lB;

  for (int t = 0; t < T; ++t) {
    const bool last = (t == T - 1);
    i32x16 hh, c1;

    // ---- n2 = clamp(drive + s1 @ W3^T) ----
    #pragma unroll
    for (int r = 0; r < 16; ++r) { hh[r] = 0; c1[r] = 0; }
    {
      const u8* ah = s1ch + m * 256;
      const u8* al = s1cl + m * 256;
      #pragma unroll
      for (int kt = 0; kt < 8; ++kt) {
        const int off = (((2 * kt + g) ^ rs4) << 4);
        i32x4 Ah = *(const i32x4*)(ah + off);
        i32x4 Al = *(const i32x4*)(al + off);
        hh = mfma_i8_32(Ah, w3F[kt], hh);
        c1 = mfma_i8_32(Al, w3F[kt], c1);
      }
    }
    #pragma unroll
    for (int r = 0; r < 16; ++r) {
      int row = (r & 3) + 8 * (r >> 2) + 4 * g;
      int pre = dr[r] + (hh[r] << 8) + c1[r];
      int cl = min(max(pre, 0), Q25_ONE);
      int q14 = (cl + 1024) >> 11;
      int h = (q14 + 128) >> 8;
      int widx = row * 256 + (((cc ^ (row & 15)) << 4)) + cb;
      s2nh[widx] = (u8)h;
      s2nl[widx] = (u8)(q14 - (h << 8));
      if (last) out2p[row * 256] = (float)cl * 0x1p-25f;
    }

    // ---- n1 = clamp(b2 + s0 @ W1^T + s2 @ W2^T) ----
    #pragma unroll
    for (int r = 0; r < 16; ++r) { hh[r] = 0; c1[r] = 0; }
    {   // s0 term: one K=32 slice (k>=10 zero-padded)
      i32x4 Ah = *(const i32x4*)(s0ch + m * 32 + g * 16);
      i32x4 Al = *(const i32x4*)(s0cl + m * 32 + g * 16);
      hh = mfma_i8_32(Ah, w1F, hh);
      c1 = mfma_i8_32(Al, w1F, c1);
    }
    {
      const u8* ah = s2ch + m * 256;
      const u8* al = s2cl + m * 256;
      #pragma unroll
      for (int kt = 0; kt < 8; ++kt) {
        const int off = (((2 * kt + g) ^ rs4) << 4);
        i32x4 Ah = *(const i32x4*)(ah + off);
        i32x4 Al = *(const i32x4*)(al + off);
        hh = mfma_i8_32(Ah, w2F[kt], hh);
        c1 = mfma_i8_32(Al, w2F[kt], c1);
      }
    }
    #pragma unroll
    for (int r = 0; r < 16; ++r) {
      int row = (r & 3) + 8 * (r >> 2) + 4 * g;
      int pre = b2i + (hh[r] << 8) + c1[r];
      int cl = min(max(pre, 0), Q25_ONE);
      int q14 = (cl + 1024) >> 11;
      int h = (q14 + 128) >> 8;
      int widx = row * 256 + (((cc ^ (row & 15)) << 4)) + cb;
      s1nh[widx] = (u8)h;
      s1nl[widx] = (u8)(q14 - (h << 8));
      if (last) out1p[row * 256] = (float)cl * 0x1p-25f;
    }

    // ---- n0 = clamp(b0 + s1 @ W0^T), waves 0-1, 16x16x64 ----
    if (w < 2) {
      const int arow = 16 * w + m16;
      const int ars = arow & 15;
      const u8* ah = s1ch + arow * 256;
      const u8* al = s1cl + arow * 256;
      i32x4 ph, p1;
      ph.x = ph.y = ph.z = ph.w = 0;
      p1.x = p1.y = p1.z = p1.w = 0;
      #pragma unroll
      for (int kt = 0; kt < 4; ++kt) {
        const int c = kt * 4 + g4;
        const int off = ((c ^ ars) << 4);
        i32x4 Ah = *(const i32x4*)(ah + off);
        i32x4 Al = *(const i32x4*)(al + off);
        i32x4 bq = *(const i32x4*)(w0s + m16 * 256 + ((c ^ m16) << 4));
        ph = mfma_i8_16(Ah, bq, ph);
        p1 = mfma_i8_16(Al, bq, p1);
      }
      #pragma unroll
      for (int r = 0; r < 4; ++r) {
        int pre = b0i + (ph[r] << 8) + p1[r];
        int cl = min(max(pre, 0), Q25_ONE);
        int q14 = (cl + 1024) >> 11;
        int h = (q14 + 128) >> 8;
        int row = 16 * w + g4 * 4 + r;
        if (m16 < 10) {
          s0nh[row * 32 + m16] = (u8)h;
          s0nl[row * 32 + m16] = (u8)(q14 - (h << 8));
          if (last) out0[(rb + row) * 10 + m16] = (float)cl * 0x1p-25f;
        }
      }
    }

    __syncthreads();   // next-state buffers fully written; old fully read
    u8* tp;
    tp = s1ch; s1ch = s1nh; s1nh = tp;
    tp = s1cl; s1cl = s1nl; s1nl = tp;
    tp = s2ch; s2ch = s2nh; s2nh = tp;
    tp = s2cl; s2cl = s2nl; s2nl = tp;
    tp = s0ch; s0ch = s0nh; s0nh = tp;
    tp = s0cl; s0cl = s0nl; s0nl = tp;
  }
}

// ---------------- launcher ---------------------------------------------------
extern "C" void kernel_launch(void* const* d_in, const int* in_sizes, int n_in,
                              void* d_out, int out_size, void* d_ws, size_t ws_size,
                              hipStream_t stream) {
  const float* data = (const float*)d_in[0];
  const float* s0g  = (const float*)d_in[1];
  const float* s1g  = (const float*)d_in[2];
  const float* s2g  = (const float*)d_in[3];
  const float* W0   = (const float*)d_in[4];
  const float* b0   = (const float*)d_in[5];
  const float* W1   = (const float*)d_in[6];
  const float* W2   = (const float*)d_in[7];
  const float* b2   = (const float*)d_in[8];
  const float* W3   = (const float*)d_in[9];
  const float* W4   = (const float*)d_in[10];
  const float* b4   = (const float*)d_in[11];
  const int*   Tp   = (const int*)d_in[12];

  char* ws = (char*)d_ws;
  int* drive = (int*)ws;                                      // 16 MB, i32 Q25
  size_t off = 16777216;
  signed char* w2q = (signed char*)(ws + off); off += 65536;
  signed char* w3q = (signed char*)(ws + off); off += 65536;
  signed char* w0q = (signed char*)(ws + off); off += 4096;
  signed char* w1q = (signed char*)(ws + off); off += 8192;
  u16* w4h = (u16*)(ws + off); off += 401408;
  u16* w4l = (u16*)(ws + off); off += 401408;
  float* b0p = (float*)(ws + off); off += 64;

  float* out0 = (float*)d_out;
  float* out1 = out0 + 16384 * 10;
  float* out2 = out1 + 16384 * 256;

  hipFuncSetAttribute((const void*)k_main,
                      hipFuncAttributeMaxDynamicSharedMemorySize, 73728);

  k_prep_w<<<784, 256, 0, stream>>>(W2, W3, W4, W0, w2q, w3q, w0q, w4h, w4l);
  k_prep_small<<<33, 256, 0, stream>>>(W1, b0, w1q, b0p);
  k_drive<<<256, 256, 0, stream>>>(data, w4h, w4l, b4, drive);
  k_main<<<512, 512, 73728, stream>>>(s0g, s1g, s2g, b2, Tp,
      w2q, w3q, w0q, w1q, b0p, drive, out0, out1, out2);
}

// Round 13
// 364.364 us; speedup vs baseline: 3.6777x; 1.0335x over previous
//
#include <hip/hip_runtime.h>

typedef __attribute__((ext_vector_type(8)))  short s8b;      // 8 x bf16
typedef __attribute__((ext_vector_type(16))) float v16f;     // 32x32 f32 acc
typedef __attribute__((ext_vector_type(4)))  float v4f;
typedef __attribute__((ext_vector_type(4)))  unsigned int u32x4;
typedef __attribute__((ext_vector_type(4)))  int i32x4;      // 16 x i8 operand
typedef __attribute__((ext_vector_type(16))) int i32x16;     // 32x32 i32 acc
typedef unsigned short u16;
typedef unsigned char u8;
typedef unsigned int u32;

#define Q25_ONE (1 << 25)

__device__ __forceinline__ void split1(float f, u16 &h, u16 &l) {
  unsigned u = __builtin_bit_cast(unsigned, f);
  unsigned hu = u & 0xffff0000u;
  float lf = f - __builtin_bit_cast(float, hu);
  h = (u16)(u >> 16);
  l = (u16)(__builtin_bit_cast(unsigned, lf) >> 16);
}

__device__ __forceinline__ v16f mfma32bf(s8b a, s8b b, v16f c) {
  return __builtin_amdgcn_mfma_f32_32x32x16_bf16(a, b, c, 0, 0, 0);
}
__device__ __forceinline__ i32x16 mfma_i8_32(i32x4 a, i32x4 b, i32x16 c) {
  return __builtin_amdgcn_mfma_i32_32x32x32_i8(a, b, c, 0, 0, 0);
}
__device__ __forceinline__ i32x4 mfma_i8_16(i32x4 a, i32x4 b, i32x4 c) {
  return __builtin_amdgcn_mfma_i32_16x16x64_i8(a, b, c, 0, 0, 0);
}

// ---------------- prep kernels ----------------------------------------------
// W2/W3 row-major i8 Q11; W0 padded [16][256] i8 Q11; W4 -> bf16 h/l
__global__ void k_prep_w(const float* __restrict__ W2, const float* __restrict__ W3,
                         const float* __restrict__ W4, const float* __restrict__ W0,
                         signed char* __restrict__ w2q, signed char* __restrict__ w3q,
                         signed char* __restrict__ w0q,
                         u16* __restrict__ w4h, u16* __restrict__ w4l) {
  int i = blockIdx.x * 256 + threadIdx.x;
  if (i < 65536) {
    int q = (int)rintf(W2[i] * 2048.0f);
    q = min(max(q, -127), 127); w2q[i] = (signed char)q;
    q = (int)rintf(W3[i] * 2048.0f);
    q = min(max(q, -127), 127); w3q[i] = (signed char)q;
  }
  if (i < 4096) {                           // W0 padded [16][256]
    int n = i >> 8, k = i & 255;
    float v = (n < 10) ? W0[n * 256 + k] : 0.0f;
    int q = (int)rintf(v * 2048.0f);
    q = min(max(q, -127), 127); w0q[i] = (signed char)q;
  }
  if (i < 200704) {
    u16 h, lo;
    split1(W4[i], h, lo); w4h[i] = h; w4l[i] = lo;
  }
}

// W1 padded [256 out][32 k] i8 Q11 (k<10 valid); b0 padded [16]
__global__ void k_prep_small(const float* __restrict__ W1, const float* __restrict__ b0,
                             signed char* __restrict__ w1q, float* __restrict__ b0p) {
  int i = blockIdx.x * 256 + threadIdx.x;
  if (i < 8192) {
    int n = i >> 5, k = i & 31;
    float v = (k < 10) ? W1[n * 10 + k] : 0.0f;
    int q = (int)rintf(v * 2048.0f);
    q = min(max(q, -127), 127); w1q[i] = (signed char)q;
  } else if (i < 8208) {
    int k = i - 8192;
    b0p[k] = (k < 10) ? b0[k] : 0.0f;
  }
}

// ---------------- drive = data @ W4^T + b4 (bf16 3-pass, once) ---------------
__device__ __forceinline__ void split_pack8(v4f x0, v4f x1, s8b &hi, s8b &lo) {
  float f[8];
  #pragma unroll
  for (int j = 0; j < 4; ++j) { f[j] = x0[j]; f[4 + j] = x1[j]; }
  u32x4 vh, vl;
  #pragma unroll
  for (int j = 0; j < 4; ++j) {
    unsigned u0 = __builtin_bit_cast(unsigned, f[2 * j]);
    unsigned u1 = __builtin_bit_cast(unsigned, f[2 * j + 1]);
    unsigned h0 = u0 & 0xffff0000u, h1 = u1 & 0xffff0000u;
    float l0 = f[2 * j]     - __builtin_bit_cast(float, h0);
    float l1 = f[2 * j + 1] - __builtin_bit_cast(float, h1);
    vh[j] = (u0 >> 16) | h1;
    vl[j] = (__builtin_bit_cast(unsigned, l0) >> 16) |
            (__builtin_bit_cast(unsigned, l1) & 0xffff0000u);
  }
  hi = __builtin_bit_cast(s8b, vh);
  lo = __builtin_bit_cast(s8b, vl);
}

__global__ void __launch_bounds__(256, 1) k_drive(
    const float* __restrict__ data, const u16* __restrict__ w4h,
    const u16* __restrict__ w4l, const float* __restrict__ b4,
    int* __restrict__ drive) {
  const int tid = threadIdx.x;
  const int w = tid >> 6, l = tid & 63;
  const int m = l & 31, g = l >> 5;
  const int rb = blockIdx.x * 64;
  const int nbase = w * 64;
  float b4v0 = b4[nbase + m], b4v1 = b4[nbase + 32 + m];
  v16f acc[2][2];
  #pragma unroll
  for (int r = 0; r < 16; ++r) {
    acc[0][0][r] = b4v0; acc[0][1][r] = b4v1;
    acc[1][0][r] = b4v0; acc[1][1][r] = b4v1;
  }
  for (int kt = 0; kt < 49; ++kt) {
    int k0 = kt * 16 + g * 8;
    s8b aH[2], aL[2], bH[2], bL[2];
    #pragma unroll
    for (int mt = 0; mt < 2; ++mt) {
      const float* p = data + (size_t)(rb + 32 * mt + m) * 784 + k0;
      v4f x0 = *(const v4f*)p;
      v4f x1 = *(const v4f*)(p + 4);
      split_pack8(x0, x1, aH[mt], aL[mt]);
    }
    #pragma unroll
    for (int nt = 0; nt < 2; ++nt) {
      int off = (nbase + 32 * nt + m) * 784 + k0;
      bH[nt] = *(const s8b*)(w4h + off);
      bL[nt] = *(const s8b*)(w4l + off);
    }
    #pragma unroll
    for (int mt = 0; mt < 2; ++mt)
      #pragma unroll
      for (int nt = 0; nt < 2; ++nt) {
        acc[mt][nt] = mfma32bf(aH[mt], bH[nt], acc[mt][nt]);
        acc[mt][nt] = mfma32bf(aL[mt], bH[nt], acc[mt][nt]);
        acc[mt][nt] = mfma32bf(aH[mt], bL[nt], acc[mt][nt]);
      }
  }
  #pragma unroll
  for (int mt = 0; mt < 2; ++mt)
    #pragma unroll
    for (int nt = 0; nt < 2; ++nt)
      #pragma unroll
      for (int r = 0; r < 16; ++r) {
        int row = rb + 32 * mt + (r & 3) + 8 * (r >> 2) + 4 * g;
        int col = nbase + 32 * nt + m;
        drive[(size_t)row * 256 + col] = (int)rintf(acc[mt][nt][r] * 33554432.0f);
      }
}

// ---------------- main persistent stepper ------------------------------------
// Swapped-operand MFMA: A = weights (regs), B = state (LDS).
// D: lane = state-row m, regs = 16 output cols in 4 contiguous quads
// -> vectorized b32 state write-back.
__global__ void __launch_bounds__(512, 2) k_main(
    const float* __restrict__ s0g, const float* __restrict__ s1g,
    const float* __restrict__ s2g, const float* __restrict__ b2,
    const int* __restrict__ Tp,
    const signed char* __restrict__ w2q, const signed char* __restrict__ w3q,
    const signed char* __restrict__ w0q, const signed char* __restrict__ w1q,
    const float* __restrict__ b0p, const int* __restrict__ drive,
    float* __restrict__ out0, float* __restrict__ out1, float* __restrict__ out2) {
  extern __shared__ u8 sm8[];
  u8* s1hA = sm8;                 // [32][256] i8, 8 KB each
  u8* s1lA = sm8 + 8192;
  u8* s2hA = sm8 + 16384;
  u8* s2lA = sm8 + 24576;
  u8* s1hB = sm8 + 32768;
  u8* s1lB = sm8 + 40960;
  u8* s2hB = sm8 + 49152;
  u8* s2lB = sm8 + 57344;
  u8* s0hA = sm8 + 65536;         // [32][48] i8, 1536 B each (k padded)
  u8* s0lA = sm8 + 67072;
  u8* s0hB = sm8 + 68608;
  u8* s0lB = sm8 + 70144;
  u8* w0s  = sm8 + 71680;         // [16][256] i8 swizzled, 4 KB
  // total 75776 B

  const int tid = threadIdx.x;
  const int w = tid >> 6, l = tid & 63;
  const int m = l & 31, g = l >> 5;
  const int m16 = l & 15, g4 = l >> 4;
  const int rb = blockIdx.x * 32;

  // ---- stage weights into registers (A-operand fragments) ----
  i32x4 w2F[8], w3F[8], w1F;
  {
    const int wo = (w * 32 + m) * 256 + g * 16;   // A row n = w*32+m
    #pragma unroll
    for (int kt = 0; kt < 8; ++kt) {
      w2F[kt] = *(const i32x4*)(w2q + wo + kt * 32);
      w3F[kt] = *(const i32x4*)(w3q + wo + kt * 32);
    }
    w1F = *(const i32x4*)(w1q + (w * 32 + m) * 32 + g * 16);
  }

  // ---- init LDS states (h/l split, 16B-chunk XOR swizzle by row&15) ----
  for (int i = tid; i < 8192; i += 512) {
    int row = i >> 8, c = i & 255;
    int idx = row * 256 + ((((c >> 4) ^ (row & 15)) << 4)) + (c & 15);
    int q = (int)rintf(s1g[(size_t)(rb + row) * 256 + c] * 16384.0f);
    int h = (q + 128) >> 8;
    s1hA[idx] = (u8)h; s1lA[idx] = (u8)(q - (h << 8));
    q = (int)rintf(s2g[(size_t)(rb + row) * 256 + c] * 16384.0f);
    h = (q + 128) >> 8;
    s2hA[idx] = (u8)h; s2lA[idx] = (u8)(q - (h << 8));
  }
  for (int i = tid; i < 1536; i += 512) {       // [32][48], pad zero
    int row = i / 48, c = i - row * 48;
    float v = (c < 10) ? s0g[(rb + row) * 10 + c] : 0.0f;
    int q = (int)rintf(v * 16384.0f);
    int h = (q + 128) >> 8;
    s0hA[i] = (u8)h; s0lA[i] = (u8)(q - (h << 8));
    s0hB[i] = 0; s0lB[i] = 0;
  }
  if (tid < 256) {                  // stage W0 into LDS, swizzled 16B chunks
    int r = tid >> 4, c = tid & 15;
    int dst = r * 256 + ((c ^ r) << 4);
    *(i32x4*)(w0s + dst) = *(const i32x4*)(w0q + r * 256 + c * 16);
  }

  // per-lane resident epilogue data: this lane owns state-row m,
  // output cols n = w*32 + 8*j + 4*g + e  (j=0..3 quads, e=0..3)
  int dr[16], b2r[16];
  {
    const int* drow = drive + (size_t)(rb + m) * 256 + w * 32 + 4 * g;
    const float* b2p = b2 + w * 32 + 4 * g;
    #pragma unroll
    for (int j = 0; j < 4; ++j) {
      i32x4 t = *(const i32x4*)(drow + 8 * j);
      #pragma unroll
      for (int e = 0; e < 4; ++e) {
        dr[j * 4 + e] = t[e];
        b2r[j * 4 + e] = (int)rintf(b2p[8 * j + e] * 33554432.0f);
      }
    }
  }
  int b0r[4];
  if (w < 2) {
    #pragma unroll
    for (int e = 0; e < 4; ++e)
      b0r[e] = (int)rintf(b0p[4 * g4 + e] * 33554432.0f);
  }

  // state write-back offsets: row m, chunk (w*2 + (j>>1)) swizzled, +((8j+4g)&15)
  int wa[4];
  #pragma unroll
  for (int j = 0; j < 4; ++j) {
    int cglob = w * 2 + (j >> 1);
    wa[j] = m * 256 + (((cglob ^ (m & 15))) << 4) + ((8 * j + 4 * g) & 15);
  }

  const int T = Tp[0];
  const int rs4 = m & 15;                   // B-read swizzle nibble
  float* out1p = out1 + (size_t)(rb + m) * 256 + w * 32 + 4 * g;
  float* out2p = out2 + (size_t)(rb + m) * 256 + w * 32 + 4 * g;
  __syncthreads();

  u8 *s1ch = s1hA, *s1cl = s1lA, *s2ch = s2hA, *s2cl = s2lA;
  u8 *s1nh = s1hB, *s1nl = s1lB, *s2nh = s2hB, *s2nl = s2lB;
  u8 *s0ch = s0hA, *s0cl = s0lA, *s0nh = s0hB, *s0nl = s0lB;

  for (int t = 0; t < T; ++t) {
    const bool last = (t == T - 1);
    i32x16 hh, c1;

    // ---- n2 = clamp(drive + s1 @ W3^T)  [computed transposed] ----
    #pragma unroll
    for (int r = 0; r < 16; ++r) { hh[r] = 0; c1[r] = 0; }
    {
      const u8* bh = s1ch + m * 256;
      const u8* bl = s1cl + m * 256;
      #pragma unroll
      for (int kt = 0; kt < 8; ++kt) {
        const int off = (((2 * kt + g) ^ rs4) << 4);
        i32x4 Bh = *(const i32x4*)(bh + off);
        i32x4 Bl = *(const i32x4*)(bl + off);
        hh = mfma_i8_32(w3F[kt], Bh, hh);
        c1 = mfma_i8_32(w3F[kt], Bl, c1);
      }
    }
    #pragma unroll
    for (int j = 0; j < 4; ++j) {
      u32 hq = 0, lq = 0;
      int cls[4];
      #pragma unroll
      for (int e = 0; e < 4; ++e) {
        int r = j * 4 + e;
        int pre = dr[r] + (hh[r] << 8) + c1[r];
        int cl = min(max(pre, 0), Q25_ONE);
        cls[e] = cl;
        int q14 = (cl + 1024) >> 11;
        int h = (q14 + 128) >> 8;
        int lo = q14 - (h << 8);
        hq |= (u32)(h & 0xff) << (8 * e);
        lq |= (u32)(lo & 0xff) << (8 * e);
      }
      *(u32*)(s2nh + wa[j]) = hq;
      *(u32*)(s2nl + wa[j]) = lq;
      if (last) {
        v4f ov;
        #pragma unroll
        for (int e = 0; e < 4; ++e) ov[e] = (float)cls[e] * 0x1p-25f;
        *(v4f*)(out2p + 8 * j) = ov;
      }
    }

    // ---- n1 = clamp(b2 + s0 @ W1^T + s2 @ W2^T) ----
    #pragma unroll
    for (int r = 0; r < 16; ++r) { hh[r] = 0; c1[r] = 0; }
    {   // s0 term: one K=32 slice (k>=10 zero-padded)
      i32x4 Bh = *(const i32x4*)(s0ch + m * 48 + g * 16);
      i32x4 Bl = *(const i32x4*)(s0cl + m * 48 + g * 16);
      hh = mfma_i8_32(w1F, Bh, hh);
      c1 = mfma_i8_32(w1F, Bl, c1);
    }
    {
      const u8* bh = s2ch + m * 256;
      const u8* bl = s2cl + m * 256;
      #pragma unroll
      for (int kt = 0; kt < 8; ++kt) {
        const int off = (((2 * kt + g) ^ rs4) << 4);
        i32x4 Bh = *(const i32x4*)(bh + off);
        i32x4 Bl = *(const i32x4*)(bl + off);
        hh = mfma_i8_32(w2F[kt], Bh, hh);
        c1 = mfma_i8_32(w2F[kt], Bl, c1);
      }
    }
    #pragma unroll
    for (int j = 0; j < 4; ++j) {
      u32 hq = 0, lq = 0;
      int cls[4];
      #pragma unroll
      for (int e = 0; e < 4; ++e) {
        int r = j * 4 + e;
        int pre = b2r[r] + (hh[r] << 8) + c1[r];
        int cl = min(max(pre, 0), Q25_ONE);
        cls[e] = cl;
        int q14 = (cl + 1024) >> 11;
        int h = (q14 + 128) >> 8;
        int lo = q14 - (h << 8);
        hq |= (u32)(h & 0xff) << (8 * e);
        lq |= (u32)(lo & 0xff) << (8 * e);
      }
      *(u32*)(s1nh + wa[j]) = hq;
      *(u32*)(s1nl + wa[j]) = lq;
      if (last) {
        v4f ov;
        #pragma unroll
        for (int e = 0; e < 4; ++e) ov[e] = (float)cls[e] * 0x1p-25f;
        *(v4f*)(out1p + 8 * j) = ov;
      }
    }

    // ---- n0 = clamp(b0 + s1 @ W0^T), waves 0-1, 16x16x64 swapped ----
    if (w < 2) {
      const int arow = 16 * w + m16;          // lane's state row
      const int ars = arow & 15;
      const u8* bh = s1ch + arow * 256;
      const u8* bl = s1cl + arow * 256;
      i32x4 ph, p1;
      ph.x = ph.y = ph.z = ph.w = 0;
      p1.x = p1.y = p1.z = p1.w = 0;
      #pragma unroll
      for (int kt = 0; kt < 4; ++kt) {
        const int c = kt * 4 + g4;
        const int off = ((c ^ ars) << 4);
        i32x4 Bh = *(const i32x4*)(bh + off);
        i32x4 Bl = *(const i32x4*)(bl + off);
        i32x4 aw = *(const i32x4*)(w0s + m16 * 256 + ((c ^ m16) << 4));
        ph = mfma_i8_16(aw, Bh, ph);
        p1 = mfma_i8_16(aw, Bl, p1);
      }
      // lane holds out0[row=arow][n = 4*g4 + e], e=0..3
      u32 hq = 0, lq = 0;
      int cls[4];
      #pragma unroll
      for (int e = 0; e < 4; ++e) {
        int pre = b0r[e] + (ph[e] << 8) + p1[e];
        int cl = min(max(pre, 0), Q25_ONE);
        cls[e] = cl;
        int q14 = (cl + 1024) >> 11;
        int h = (q14 + 128) >> 8;
        int lo = q14 - (h << 8);
        hq |= (u32)(h & 0xff) << (8 * e);
        lq |= (u32)(lo & 0xff) << (8 * e);
      }
      if (g4 < 2) {                     // n = 0..7: full dword
        *(u32*)(s0nh + arow * 48 + 4 * g4) = hq;
        *(u32*)(s0nl + arow * 48 + 4 * g4) = lq;
      } else if (g4 == 2) {             // n = 8,9 only
        *(u16*)(s0nh + arow * 48 + 8) = (u16)(hq & 0xffff);
        *(u16*)(s0nl + arow * 48 + 8) = (u16)(lq & 0xffff);
      }
      if (last) {
        #pragma unroll
        for (int e = 0; e < 4; ++e) {
          int n = 4 * g4 + e;
          if (n < 10) out0[(rb + arow) * 10 + n] = (float)cls[e] * 0x1p-25f;
        }
      }
    }

    __syncthreads();   // next-state buffers fully written; old fully read
    u8* tp;
    tp = s1ch; s1ch = s1nh; s1nh = tp;
    tp = s1cl; s1cl = s1nl; s1nl = tp;
    tp = s2ch; s2ch = s2nh; s2nh = tp;
    tp = s2cl; s2cl = s2nl; s2nl = tp;
    tp = s0ch; s0ch = s0nh; s0nh = tp;
    tp = s0cl; s0cl = s0nl; s0nl = tp;
  }
}

// ---------------- launcher ---------------------------------------------------
extern "C" void kernel_launch(void* const* d_in, const int* in_sizes, int n_in,
                              void* d_out, int out_size, void* d_ws, size_t ws_size,
                              hipStream_t stream) {
  const float* data = (const float*)d_in[0];
  const float* s0g  = (const float*)d_in[1];
  const float* s1g  = (const float*)d_in[2];
  const float* s2g  = (const float*)d_in[3];
  const float* W0   = (const float*)d_in[4];
  const float* b0   = (const float*)d_in[5];
  const float* W1   = (const float*)d_in[6];
  const float* W2   = (const float*)d_in[7];
  const float* b2   = (const float*)d_in[8];
  const float* W3   = (const float*)d_in[9];
  const float* W4   = (const float*)d_in[10];
  const float* b4   = (const float*)d_in[11];
  const int*   Tp   = (const int*)d_in[12];

  char* ws = (char*)d_ws;
  int* drive = (int*)ws;                                      // 16 MB, i32 Q25
  size_t off = 16777216;
  signed char* w2q = (signed char*)(ws + off); off += 65536;
  signed char* w3q = (signed char*)(ws + off); off += 65536;
  signed char* w0q = (signed char*)(ws + off); off += 4096;
  signed char* w1q = (signed char*)(ws + off); off += 8192;
  u16* w4h = (u16*)(ws + off); off += 401408;
  u16* w4l = (u16*)(ws + off); off += 401408;
  float* b0p = (float*)(ws + off); off += 64;

  float* out0 = (float*)d_out;
  float* out1 = out0 + 16384 * 10;
  float* out2 = out1 + 16384 * 256;

  hipFuncSetAttribute((const void*)k_main,
                      hipFuncAttributeMaxDynamicSharedMemorySize, 75776);

  k_prep_w<<<784, 256, 0, stream>>>(W2, W3, W4, W0, w2q, w3q, w0q, w4h, w4l);
  k_prep_small<<<33, 256, 0, stream>>>(W1, b0, w1q, b0p);
  k_drive<<<256, 256, 0, stream>>>(data, w4h, w4l, b4, drive);
  k_main<<<512, 512, 75776, stream>>>(s0g, s1g, s2g, b2, Tp,
      w2q, w3q, w0q, w1q, b0p, drive, out0, out1, out2);
}

// Round 14
// 340.135 us; speedup vs baseline: 3.9397x; 1.0712x over previous
//
#include <hip/hip_runtime.h>

typedef __attribute__((ext_vector_type(8)))  short s8b;      // 8 x bf16
typedef __attribute__((ext_vector_type(16))) float v16f;     // 32x32 f32 acc
typedef __attribute__((ext_vector_type(4)))  float v4f;
typedef __attribute__((ext_vector_type(4)))  unsigned int u32x4;
typedef __attribute__((ext_vector_type(4)))  int i32x4;      // 16 x i8 operand
typedef __attribute__((ext_vector_type(16))) int i32x16;     // 32x32 i32 acc
typedef unsigned short u16;
typedef unsigned char u8;
typedef unsigned int u32;

#define Q25_ONE (1 << 25)

__device__ __forceinline__ void split1(float f, u16 &h, u16 &l) {
  unsigned u = __builtin_bit_cast(unsigned, f);
  unsigned hu = u & 0xffff0000u;
  float lf = f - __builtin_bit_cast(float, hu);
  h = (u16)(u >> 16);
  l = (u16)(__builtin_bit_cast(unsigned, lf) >> 16);
}

__device__ __forceinline__ v16f mfma32bf(s8b a, s8b b, v16f c) {
  return __builtin_amdgcn_mfma_f32_32x32x16_bf16(a, b, c, 0, 0, 0);
}
__device__ __forceinline__ i32x16 mfma_i8_32(i32x4 a, i32x4 b, i32x16 c) {
  return __builtin_amdgcn_mfma_i32_32x32x32_i8(a, b, c, 0, 0, 0);
}
__device__ __forceinline__ i32x4 mfma_i8_16(i32x4 a, i32x4 b, i32x4 c) {
  return __builtin_amdgcn_mfma_i32_16x16x64_i8(a, b, c, 0, 0, 0);
}

// pack low bytes of 4 ints into one dword: b0 | b1<<8 | b2<<16 | b3<<24
__device__ __forceinline__ u32 pack4(int b0, int b1, int b2, int b3) {
  u32 t0 = __builtin_amdgcn_perm((u32)b1, (u32)b0, 0x0C0C0400u);
  u32 t1 = __builtin_amdgcn_perm((u32)b3, (u32)b2, 0x0C0C0400u);
  return __builtin_amdgcn_perm(t1, t0, 0x05040100u);
}

// ---------------- prep kernels ----------------------------------------------
// W2/W3 row-major i8 Q11; W0 padded [16][256] i8 Q11; W4 -> bf16 h/l
__global__ void k_prep_w(const float* __restrict__ W2, const float* __restrict__ W3,
                         const float* __restrict__ W4, const float* __restrict__ W0,
                         signed char* __restrict__ w2q, signed char* __restrict__ w3q,
                         signed char* __restrict__ w0q,
                         u16* __restrict__ w4h, u16* __restrict__ w4l) {
  int i = blockIdx.x * 256 + threadIdx.x;
  if (i < 65536) {
    int q = (int)rintf(W2[i] * 2048.0f);
    q = min(max(q, -127), 127); w2q[i] = (signed char)q;
    q = (int)rintf(W3[i] * 2048.0f);
    q = min(max(q, -127), 127); w3q[i] = (signed char)q;
  }
  if (i < 4096) {                           // W0 padded [16][256]
    int n = i >> 8, k = i & 255;
    float v = (n < 10) ? W0[n * 256 + k] : 0.0f;
    int q = (int)rintf(v * 2048.0f);
    q = min(max(q, -127), 127); w0q[i] = (signed char)q;
  }
  if (i < 200704) {
    u16 h, lo;
    split1(W4[i], h, lo); w4h[i] = h; w4l[i] = lo;
  }
}

// W1 padded [256 out][32 k] i8 Q11 (k<10 valid); b0 padded [16]
__global__ void k_prep_small(const float* __restrict__ W1, const float* __restrict__ b0,
                             signed char* __restrict__ w1q, float* __restrict__ b0p) {
  int i = blockIdx.x * 256 + threadIdx.x;
  if (i < 8192) {
    int n = i >> 5, k = i & 31;
    float v = (k < 10) ? W1[n * 10 + k] : 0.0f;
    int q = (int)rintf(v * 2048.0f);
    q = min(max(q, -127), 127); w1q[i] = (signed char)q;
  } else if (i < 8208) {
    int k = i - 8192;
    b0p[k] = (k < 10) ? b0[k] : 0.0f;
  }
}

// ---------------- drive = data @ W4^T + b4 (bf16 3-pass, once) ---------------
__device__ __forceinline__ void split_pack8(v4f x0, v4f x1, s8b &hi, s8b &lo) {
  float f[8];
  #pragma unroll
  for (int j = 0; j < 4; ++j) { f[j] = x0[j]; f[4 + j] = x1[j]; }
  u32x4 vh, vl;
  #pragma unroll
  for (int j = 0; j < 4; ++j) {
    unsigned u0 = __builtin_bit_cast(unsigned, f[2 * j]);
    unsigned u1 = __builtin_bit_cast(unsigned, f[2 * j + 1]);
    unsigned h0 = u0 & 0xffff0000u, h1 = u1 & 0xffff0000u;
    float l0 = f[2 * j]     - __builtin_bit_cast(float, h0);
    float l1 = f[2 * j + 1] - __builtin_bit_cast(float, h1);
    vh[j] = (u0 >> 16) | h1;
    vl[j] = (__builtin_bit_cast(unsigned, l0) >> 16) |
            (__builtin_bit_cast(unsigned, l1) & 0xffff0000u);
  }
  hi = __builtin_bit_cast(s8b, vh);
  lo = __builtin_bit_cast(s8b, vl);
}

__global__ void __launch_bounds__(256, 1) k_drive(
    const float* __restrict__ data, const u16* __restrict__ w4h,
    const u16* __restrict__ w4l, const float* __restrict__ b4,
    int* __restrict__ drive) {
  const int tid = threadIdx.x;
  const int w = tid >> 6, l = tid & 63;
  const int m = l & 31, g = l >> 5;
  const int rb = blockIdx.x * 64;
  const int nbase = w * 64;
  float b4v0 = b4[nbase + m], b4v1 = b4[nbase + 32 + m];
  v16f acc[2][2];
  #pragma unroll
  for (int r = 0; r < 16; ++r) {
    acc[0][0][r] = b4v0; acc[0][1][r] = b4v1;
    acc[1][0][r] = b4v0; acc[1][1][r] = b4v1;
  }
  for (int kt = 0; kt < 49; ++kt) {
    int k0 = kt * 16 + g * 8;
    s8b aH[2], aL[2], bH[2], bL[2];
    #pragma unroll
    for (int mt = 0; mt < 2; ++mt) {
      const float* p = data + (size_t)(rb + 32 * mt + m) * 784 + k0;
      v4f x0 = *(const v4f*)p;
      v4f x1 = *(const v4f*)(p + 4);
      split_pack8(x0, x1, aH[mt], aL[mt]);
    }
    #pragma unroll
    for (int nt = 0; nt < 2; ++nt) {
      int off = (nbase + 32 * nt + m) * 784 + k0;
      bH[nt] = *(const s8b*)(w4h + off);
      bL[nt] = *(const s8b*)(w4l + off);
    }
    #pragma unroll
    for (int mt = 0; mt < 2; ++mt)
      #pragma unroll
      for (int nt = 0; nt < 2; ++nt) {
        acc[mt][nt] = mfma32bf(aH[mt], bH[nt], acc[mt][nt]);
        acc[mt][nt] = mfma32bf(aL[mt], bH[nt], acc[mt][nt]);
        acc[mt][nt] = mfma32bf(aH[mt], bL[nt], acc[mt][nt]);
      }
  }
  #pragma unroll
  for (int mt = 0; mt < 2; ++mt)
    #pragma unroll
    for (int nt = 0; nt < 2; ++nt)
      #pragma unroll
      for (int r = 0; r < 16; ++r) {
        int row = rb + 32 * mt + (r & 3) + 8 * (r >> 2) + 4 * g;
        int col = nbase + 32 * nt + m;
        drive[(size_t)row * 256 + col] = (int)rintf(acc[mt][nt][r] * 33554432.0f);
      }
}

// ---------------- main persistent stepper ------------------------------------
// Swapped-operand MFMA (A=weights regs, B=state LDS), chunk-transposed state:
// state array layout [16 chunks][32 rows][16B] -> all ds_read_b128 at
// per-lane base + compile-time immediate; reads structurally conflict-free.
__global__ void __launch_bounds__(512, 2) k_main(
    const float* __restrict__ s0g, const float* __restrict__ s1g,
    const float* __restrict__ s2g, const float* __restrict__ b2,
    const int* __restrict__ Tp,
    const signed char* __restrict__ w2q, const signed char* __restrict__ w3q,
    const signed char* __restrict__ w0q, const signed char* __restrict__ w1q,
    const float* __restrict__ b0p, const int* __restrict__ drive,
    float* __restrict__ out0, float* __restrict__ out1, float* __restrict__ out2) {
  extern __shared__ u8 sm8[];
  u8* s1hA = sm8;                 // [16][32][16] i8, 8 KB each
  u8* s1lA = sm8 + 8192;
  u8* s2hA = sm8 + 16384;
  u8* s2lA = sm8 + 24576;
  u8* s1hB = sm8 + 32768;
  u8* s1lB = sm8 + 40960;
  u8* s2hB = sm8 + 49152;
  u8* s2lB = sm8 + 57344;
  u8* s0hA = sm8 + 65536;         // [32][48] i8, 1536 B each (k padded)
  u8* s0lA = sm8 + 67072;
  u8* s0hB = sm8 + 68608;
  u8* s0lB = sm8 + 70144;
  u8* w0s  = sm8 + 71680;         // [16 chunks][16 rows][16B] i8, 4 KB
  // total 75776 B

  const int tid = threadIdx.x;
  const int w = tid >> 6, l = tid & 63;
  const int m = l & 31, g = l >> 5;
  const int m16 = l & 15, g4 = l >> 4;
  const int rb = blockIdx.x * 32;

  // ---- stage weights into registers (A-operand fragments) ----
  i32x4 w2F[8], w3F[8], w1F;
  {
    const int wo = (w * 32 + m) * 256 + g * 16;   // A row n = w*32+m
    #pragma unroll
    for (int kt = 0; kt < 8; ++kt) {
      w2F[kt] = *(const i32x4*)(w2q + wo + kt * 32);
      w3F[kt] = *(const i32x4*)(w3q + wo + kt * 32);
    }
    w1F = *(const i32x4*)(w1q + (w * 32 + m) * 32 + g * 16);
  }

  // ---- init LDS states (h/l split, chunk-transposed) ----
  for (int i = tid; i < 8192; i += 512) {
    int row = i >> 8, c = i & 255;
    int idx = ((c >> 4) << 9) + row * 16 + (c & 15);   // chunk*512 + row*16 + byte
    int q = (int)rintf(s1g[(size_t)(rb + row) * 256 + c] * 16384.0f);
    int h = (q + 128) >> 8;
    s1hA[idx] = (u8)h; s1lA[idx] = (u8)(q - (h << 8));
    q = (int)rintf(s2g[(size_t)(rb + row) * 256 + c] * 16384.0f);
    h = (q + 128) >> 8;
    s2hA[idx] = (u8)h; s2lA[idx] = (u8)(q - (h << 8));
  }
  for (int i = tid; i < 1536; i += 512) {       // [32][48], pad zero
    int row = i / 48, c = i - row * 48;
    float v = (c < 10) ? s0g[(rb + row) * 10 + c] : 0.0f;
    int q = (int)rintf(v * 16384.0f);
    int h = (q + 128) >> 8;
    s0hA[i] = (u8)h; s0lA[i] = (u8)(q - (h << 8));
    s0hB[i] = 0; s0lB[i] = 0;
  }
  if (tid < 256) {                  // stage W0 chunk-transposed
    int r = tid >> 4, c = tid & 15;
    *(i32x4*)(w0s + c * 256 + r * 16) = *(const i32x4*)(w0q + r * 256 + c * 16);
  }

  // per-lane resident epilogue data: lane owns state-row m,
  // output cols n = w*32 + 8*j + 4*g + e  (j=0..3 quads, e=0..3)
  int dr[16], b2r[16];
  {
    const int* drow = drive + (size_t)(rb + m) * 256 + w * 32 + 4 * g;
    const float* b2p = b2 + w * 32 + 4 * g;
    #pragma unroll
    for (int j = 0; j < 4; ++j) {
      i32x4 t = *(const i32x4*)(drow + 8 * j);
      #pragma unroll
      for (int e = 0; e < 4; ++e) {
        dr[j * 4 + e] = t[e];
        b2r[j * 4 + e] = (int)rintf(b2p[8 * j + e] * 33554432.0f);
      }
    }
  }
  int b0r[4];
  if (w < 2) {
    #pragma unroll
    for (int e = 0; e < 4; ++e)
      b0r[e] = (int)rintf(b0p[4 * g4 + e] * 33554432.0f);
  }

  const int T = Tp[0];
  // LDS bases (all per-lane, loop-invariant; reads/writes use immediates)
  const int rdB = m * 16 + g * 512;            // gemm B-read base
  const int wrB = w * 1024 + m * 16 + 4 * g;   // state write base
  const int rdB0 = (16 * w + m16) * 16 + g4 * 512;  // n0 B-read base (waves 0-1)
  float* out1p = out1 + (size_t)(rb + m) * 256 + w * 32 + 4 * g;
  float* out2p = out2 + (size_t)(rb + m) * 256 + w * 32 + 4 * g;
  __syncthreads();

  u8 *s1ch = s1hA, *s1cl = s1lA, *s2ch = s2hA, *s2cl = s2lA;
  u8 *s1nh = s1hB, *s1nl = s1lB, *s2nh = s2hB, *s2nl = s2lB;
  u8 *s0ch = s0hA, *s0cl = s0lA, *s0nh = s0hB, *s0nl = s0lB;

  for (int t = 0; t < T; ++t) {
    const bool last = (t == T - 1);
    i32x16 hh, c1;

    // ---- n2 = clamp(drive + s1 @ W3^T)  [computed transposed] ----
    #pragma unroll
    for (int r = 0; r < 16; ++r) { hh[r] = 0; c1[r] = 0; }
    {
      const u8* bh = s1ch + rdB;
      const u8* bl = s1cl + rdB;
      #pragma unroll
      for (int kt = 0; kt < 8; ++kt) {
        i32x4 Bh = *(const i32x4*)(bh + kt * 1024);
        i32x4 Bl = *(const i32x4*)(bl + kt * 1024);
        hh = mfma_i8_32(w3F[kt], Bh, hh);
        c1 = mfma_i8_32(w3F[kt], Bl, c1);
      }
    }
    #pragma unroll
    for (int j = 0; j < 4; ++j) {
      int hb[4], lb[4], cls[4];
      #pragma unroll
      for (int e = 0; e < 4; ++e) {
        int r = j * 4 + e;
        int pre = dr[r] + (hh[r] << 8) + c1[r];
        int cl = min(max(pre, 0), Q25_ONE);
        cls[e] = cl;
        int q14 = (cl + 1024) >> 11;
        int h = (cl + 263168) >> 19;        // == (q14+128)>>8 exactly
        hb[e] = h;
        lb[e] = q14 - (h << 8);
      }
      const int wo = wrB + ((j >> 1) << 9) + ((j & 1) << 3);
      *(u32*)(s2nh + wo) = pack4(hb[0], hb[1], hb[2], hb[3]);
      *(u32*)(s2nl + wo) = pack4(lb[0], lb[1], lb[2], lb[3]);
      if (last) {
        v4f ov;
        #pragma unroll
        for (int e = 0; e < 4; ++e) ov[e] = (float)cls[e] * 0x1p-25f;
        *(v4f*)(out2p + 8 * j) = ov;
      }
    }

    // ---- n1 = clamp(b2 + s0 @ W1^T + s2 @ W2^T) ----
    #pragma unroll
    for (int r = 0; r < 16; ++r) { hh[r] = 0; c1[r] = 0; }
    {   // s0 term: one K=32 slice (k>=10 zero-padded)
      i32x4 Bh = *(const i32x4*)(s0ch + m * 48 + g * 16);
      i32x4 Bl = *(const i32x4*)(s0cl + m * 48 + g * 16);
      hh = mfma_i8_32(w1F, Bh, hh);
      c1 = mfma_i8_32(w1F, Bl, c1);
    }
    {
      const u8* bh = s2ch + rdB;
      const u8* bl = s2cl + rdB;
      #pragma unroll
      for (int kt = 0; kt < 8; ++kt) {
        i32x4 Bh = *(const i32x4*)(bh + kt * 1024);
        i32x4 Bl = *(const i32x4*)(bl + kt * 1024);
        hh = mfma_i8_32(w2F[kt], Bh, hh);
        c1 = mfma_i8_32(w2F[kt], Bl, c1);
      }
    }
    #pragma unroll
    for (int j = 0; j < 4; ++j) {
      int hb[4], lb[4], cls[4];
      #pragma unroll
      for (int e = 0; e < 4; ++e) {
        int r = j * 4 + e;
        int pre = b2r[r] + (hh[r] << 8) + c1[r];
        int cl = min(max(pre, 0), Q25_ONE);
        cls[e] = cl;
        int q14 = (cl + 1024) >> 11;
        int h = (cl + 263168) >> 19;
        hb[e] = h;
        lb[e] = q14 - (h << 8);
      }
      const int wo = wrB + ((j >> 1) << 9) + ((j & 1) << 3);
      *(u32*)(s1nh + wo) = pack4(hb[0], hb[1], hb[2], hb[3]);
      *(u32*)(s1nl + wo) = pack4(lb[0], lb[1], lb[2], lb[3]);
      if (last) {
        v4f ov;
        #pragma unroll
        for (int e = 0; e < 4; ++e) ov[e] = (float)cls[e] * 0x1p-25f;
        *(v4f*)(out1p + 8 * j) = ov;
      }
    }

    // ---- n0 = clamp(b0 + s1 @ W0^T), waves 0-1, 16x16x64 swapped ----
    if (w < 2) {
      const int arow = 16 * w + m16;          // lane's state row
      const u8* bh = s1ch + rdB0;
      const u8* bl = s1cl + rdB0;
      i32x4 ph, p1;
      ph.x = ph.y = ph.z = ph.w = 0;
      p1.x = p1.y = p1.z = p1.w = 0;
      #pragma unroll
      for (int kt = 0; kt < 4; ++kt) {
        i32x4 Bh = *(const i32x4*)(bh + kt * 2048);
        i32x4 Bl = *(const i32x4*)(bl + kt * 2048);
        i32x4 aw = *(const i32x4*)(w0s + m16 * 16 + g4 * 256 + kt * 1024);
        ph = mfma_i8_16(aw, Bh, ph);
        p1 = mfma_i8_16(aw, Bl, p1);
      }
      // lane holds out0[row=arow][n = 4*g4 + e], e=0..3
      int hb[4], lb[4], cls[4];
      #pragma unroll
      for (int e = 0; e < 4; ++e) {
        int pre = b0r[e] + (ph[e] << 8) + p1[e];
        int cl = min(max(pre, 0), Q25_ONE);
        cls[e] = cl;
        int q14 = (cl + 1024) >> 11;
        int h = (cl + 263168) >> 19;
        hb[e] = h;
        lb[e] = q14 - (h << 8);
      }
      u32 hq = pack4(hb[0], hb[1], hb[2], hb[3]);
      u32 lq = pack4(lb[0], lb[1], lb[2], lb[3]);
      if (g4 < 2) {                     // n = 0..7: full dword
        *(u32*)(s0nh + arow * 48 + 4 * g4) = hq;
        *(u32*)(s0nl + arow * 48 + 4 * g4) = lq;
      } else if (g4 == 2) {             // n = 8,9 only
        *(u16*)(s0nh + arow * 48 + 8) = (u16)(hq & 0xffff);
        *(u16*)(s0nl + arow * 48 + 8) = (u16)(lq & 0xffff);
      }
      if (last) {
        #pragma unroll
        for (int e = 0; e < 4; ++e) {
          int n = 4 * g4 + e;
          if (n < 10) out0[(rb + arow) * 10 + n] = (float)cls[e] * 0x1p-25f;
        }
      }
    }

    __syncthreads();   // next-state buffers fully written; old fully read
    u8* tp;
    tp = s1ch; s1ch = s1nh; s1nh = tp;
    tp = s1cl; s1cl = s1nl; s1nl = tp;
    tp = s2ch; s2ch = s2nh; s2nh = tp;
    tp = s2cl; s2cl = s2nl; s2nl = tp;
    tp = s0ch; s0ch = s0nh; s0nh = tp;
    tp = s0cl; s0cl = s0nl; s0nl = tp;
  }
}

// ---------------- launcher ---------------------------------------------------
extern "C" void kernel_launch(void* const* d_in, const int* in_sizes, int n_in,
                              void* d_out, int out_size, void* d_ws, size_t ws_size,
                              hipStream_t stream) {
  const float* data = (const float*)d_in[0];
  const float* s0g  = (const float*)d_in[1];
  const float* s1g  = (const float*)d_in[2];
  const float* s2g  = (const float*)d_in[3];
  const float* W0   = (const float*)d_in[4];
  const float* b0   = (const float*)d_in[5];
  const float* W1   = (const float*)d_in[6];
  const float* W2   = (const float*)d_in[7];
  const float* b2   = (const float*)d_in[8];
  const float* W3   = (const float*)d_in[9];
  const float* W4   = (const float*)d_in[10];
  const float* b4   = (const float*)d_in[11];
  const int*   Tp   = (const int*)d_in[12];

  char* ws = (char*)d_ws;
  int* drive = (int*)ws;                                      // 16 MB, i32 Q25
  size_t off = 16777216;
  signed char* w2q = (signed char*)(ws + off); off += 65536;
  signed char* w3q = (signed char*)(ws + off); off += 65536;
  signed char* w0q = (signed char*)(ws + off); off += 4096;
  signed char* w1q = (signed char*)(ws + off); off += 8192;
  u16* w4h = (u16*)(ws + off); off += 401408;
  u16* w4l = (u16*)(ws + off); off += 401408;
  float* b0p = (float*)(ws + off); off += 64;

  float* out0 = (float*)d_out;
  float* out1 = out0 + 16384 * 10;
  float* out2 = out1 + 16384 * 256;

  hipFuncSetAttribute((const void*)k_main,
                      hipFuncAttributeMaxDynamicSharedMemorySize, 75776);

  k_prep_w<<<784, 256, 0, stream>>>(W2, W3, W4, W0, w2q, w3q, w0q, w4h, w4l);
  k_prep_small<<<33, 256, 0, stream>>>(W1, b0, w1q, b0p);
  k_drive<<<256, 256, 0, stream>>>(data, w4h, w4l, b4, drive);
  k_main<<<512, 512, 75776, stream>>>(s0g, s1g, s2g, b2, Tp,
      w2q, w3q, w0q, w1q, b0p, drive, out0, out1, out2);
}